// Round 5
// baseline (176.719 us; speedup 1.0000x reference)
//
#include <hip/hip_runtime.h>
#include <hip/hip_bf16.h>

// Problem constants
#define B_  4096
#define T_  80
#define E_  100
#define U_  64
#define G_  256    // 4*U
#define V_  10000

#define S_H  72    // hbuf row stride (bf16): 144B rows; b128 reads distribute 8 dw/bank = floor
#define AS   136   // embk emb-tile LDS stride (bf16)
#define KS2  132   // embk k1-tile ROW-major LDS stride (bf16); b64 writes at 4 dw/bank = floor
#define TS   81    // token LDS row stride (ints); odd stride spreads rows across banks
#define XS   260   // xstage row stride (floats): n*260 dw mod 32 = 4n -> b128 reads at 8 dw/bank = floor

typedef __attribute__((ext_vector_type(8))) __bf16 bf16x8;
typedef __attribute__((ext_vector_type(4))) __bf16 bf16x4;
typedef __attribute__((ext_vector_type(4))) float  floatx4;

__device__ __forceinline__ float sigmoidf_(float x) {
    return __builtin_amdgcn_rcpf(1.f + __expf(-x));
}

__device__ __forceinline__ float tanhf_(float x) {
    // 1 - 2/(e^{2x}+1): monotone, saturates correctly, no NaN
    return fmaf(-2.f, __builtin_amdgcn_rcpf(__expf(2.f * x) + 1.f), 1.f);
}

// Block-wide barrier WITHOUT the vmcnt(0) drain __syncthreads() forces.
// LDS traffic (h + xstage writes) is drained; global loads stay in flight,
// tracked by the compiler's counted s_waitcnt vmcnt(N) at first use.
__device__ __forceinline__ void block_sync_lgkm() {
    asm volatile("s_waitcnt lgkmcnt(0)\n\ts_barrier" ::: "memory");
}

// ---------------------------------------------------------------------------
// Kernel A (MFMA): embk[v][g] = b1[g] + emb[v] . k1[:,g]
// R5: k1 tile staged ROW-MAJOR in LDS (coalesced float4 reads -> bank-floor
// b64 writes). B-fragments built once via 64 ds_read_u16/lane (<=2-way
// banking). R4's transposed staging had ~32-way write conflicts (2*KS mod 32
// = 16 -> 2 banks); R1's version had 64-line divergent global scatters.
// Same bf16 rounding, same MFMA order, same stores -> bit-identical output.
// ---------------------------------------------------------------------------
__global__ __launch_bounds__(256) void embk_kernel(const float* __restrict__ emb,
                                                   const float* __restrict__ k1,
                                                   const float* __restrict__ b1,
                                                   float* __restrict__ embk) {
    __shared__ __bf16 aLDS[64 * AS];         // 17.4 KB  (emb tile, row-major)
    __shared__ __bf16 kLDS[128 * KS2];       // 33.8 KB  (k1 tile, ROW-major [k][col])

    const int tid  = threadIdx.x;
    const int lane = tid & 63;
    const int w    = tid >> 6;               // wave: owns cols n0 + [w*32, w*32+32)
    const int n    = lane & 15;
    const int kg   = lane >> 4;
    const int v0   = (blockIdx.x >> 1) * 64;
    const int n0   = (blockIdx.x & 1) * 128;
    const int nrows = min(64, V_ - v0);

    // epoch 1: zero aLDS (full) and kLDS k-pad rows [100,128)
    for (int i = tid; i < 64 * AS / 8; i += 256) {
        bf16x8 z;
#pragma unroll
        for (int jj = 0; jj < 8; ++jj) z[jj] = (__bf16)0.f;
        *(bf16x8*)(aLDS + i * 8) = z;
    }
    for (int i = tid; i < 28 * KS2; i += 256)
        kLDS[100 * KS2 + i] = (__bf16)0.f;

    const float bv0 = b1[n0 + w * 32 + n];
    const float bv1 = b1[n0 + w * 32 + 16 + n];

    __syncthreads();                         // zeroing visible before fills

    // epoch 2a: emb tile -> aLDS (row-major bf16), coalesced float4 reads
    for (int i = tid; i < nrows * 25; i += 256) {
        int r = i / 25, q = i - r * 25;
        float4 ev = *(const float4*)(emb + (long)(v0 + r) * E_ + q * 4);
        bf16x4 bv; bv[0] = (__bf16)ev.x; bv[1] = (__bf16)ev.y;
                   bv[2] = (__bf16)ev.z; bv[3] = (__bf16)ev.w;
        *(bf16x4*)(aLDS + r * AS + q * 4) = bv;
    }
    // epoch 2b: k1 tile -> kLDS ROW-major: kLDS[k][c] = bf16(k1[k][n0+c]).
    // Reads coalesced (float4 along k1 rows); b64 writes at the bank floor.
    for (int i = tid; i < 100 * 32; i += 256) {
        int k = i >> 5, cq = (i & 31) * 4;
        float4 kv = *(const float4*)(k1 + (long)k * G_ + n0 + cq);
        bf16x4 bv; bv[0] = (__bf16)kv.x; bv[1] = (__bf16)kv.y;
                   bv[2] = (__bf16)kv.z; bv[3] = (__bf16)kv.w;
        *(bf16x4*)(kLDS + k * KS2 + cq) = bv;
    }
    __syncthreads();

    // B-fragments from kLDS rows: lane (n,kg), tile ct -> col = w*32+ct*16+n,
    // k = kc*32 + kg*8 + jj. 64 one-time ds_read_u16, <=2-way banking.
    bf16x8 bfr[2][4];
#pragma unroll
    for (int ct = 0; ct < 2; ++ct)
#pragma unroll
        for (int kc = 0; kc < 4; ++kc) {
            bf16x8 s;
#pragma unroll
            for (int jj = 0; jj < 8; ++jj)
                s[jj] = kLDS[(kc * 32 + kg * 8 + jj) * KS2 + w * 32 + ct * 16 + n];
            bfr[ct][kc] = s;
        }

#pragma unroll
    for (int mt = 0; mt < 4; ++mt) {
        const __bf16* ab = aLDS + (mt * 16 + n) * AS + kg * 8;
        bf16x8 a0 = *(const bf16x8*)(ab + 0);
        bf16x8 a1 = *(const bf16x8*)(ab + 32);
        bf16x8 a2 = *(const bf16x8*)(ab + 64);
        bf16x8 a3 = *(const bf16x8*)(ab + 96);
#pragma unroll
        for (int ct = 0; ct < 2; ++ct) {
            float bv = ct ? bv1 : bv0;
            floatx4 acc = {bv, bv, bv, bv};
            acc = __builtin_amdgcn_mfma_f32_16x16x32_bf16(a0, bfr[ct][0], acc, 0, 0, 0);
            acc = __builtin_amdgcn_mfma_f32_16x16x32_bf16(a1, bfr[ct][1], acc, 0, 0, 0);
            acc = __builtin_amdgcn_mfma_f32_16x16x32_bf16(a2, bfr[ct][2], acc, 0, 0, 0);
            acc = __builtin_amdgcn_mfma_f32_16x16x32_bf16(a3, bfr[ct][3], acc, 0, 0, 0);
#pragma unroll
            for (int r = 0; r < 4; ++r) {
                int v = v0 + mt * 16 + kg * 4 + r;
                if (v < V_) embk[(long)v * G_ + n0 + w * 32 + ct * 16 + n] = acc[r];
            }
        }
    }
}

// ---------------------------------------------------------------------------
// Kernel B: recurrence via TRANSPOSED MFMA: z^T = r1^T @ h^T.
// R5 change: xk is no longer a per-lane DIVERGENT gather (4 dwordx4 x 16
// random 64B segments each -> TA serialization suspect). Per step the block
// needs 16 full 1KB embk rows; they are loaded COALESCED (thread (row,p):
// float4 at row-offset p*4 + j*64; 4 segments/instr) into ping-pong regs,
// written next step into a 3-buffer LDS xstage at the b128 bank floor, and
// consumed one step later. Buffer read at step t-1 is rewritten at t
// (separated by the step barrier -> race-free); vmcnt wait at the ds_write
// covers loads issued a full step earlier (~zero stall).
// ---------------------------------------------------------------------------
__global__ __launch_bounds__(256) void lstm_kernel(const int*   __restrict__ tokens,
                                                   const float* __restrict__ embk,
                                                   const float* __restrict__ r1,
                                                   const float* __restrict__ Wd,
                                                   const float* __restrict__ bd,
                                                   float* __restrict__ out) {
    __shared__ int    tokLDS[16 * TS];       // 5.2 KB
    __shared__ __bf16 hbuf[2][16 * S_H];     // 4.6 KB
    __shared__ float  xstage[3][16 * XS];    // 49.9 KB (3-phase rotation)

    const int tid  = threadIdx.x;
    const int lane = tid & 63;
    const int w    = tid >> 6;               // unit block [w*16, w*16+16)
    const int n    = lane & 15;              // batch row (N-operand of MFMA)
    const int kg   = lane >> 4;              // 0..3
    const int bb   = blockIdx.x * 16;
    const int prow = tid >> 4;               // producer: batch row 0..15
    const int pp   = tid & 15;               // producer: float4 slot within 256B run

    for (int i = tid; i < 16 * T_; i += 256)
        tokLDS[(i / T_) * TS + (i % T_)] = tokens[bb * T_ + i];
    for (int i = tid; i < 2 * 16 * S_H; i += 256) (&hbuf[0][0])[i] = (__bf16)0.f;

    // A-fragments = r1^T (static): tile ct covers gate-cols ct*64 + w*16 + m,
    // A[m][k] = r1[k][ct*64 + w*16 + m]; lane holds m = n, k = kc*32 + kg*8 + jj
    bf16x8 afr[4][2];
#pragma unroll
    for (int ct = 0; ct < 4; ++ct)
#pragma unroll
        for (int kc = 0; kc < 2; ++kc) {
            bf16x8 s;
#pragma unroll
            for (int jj = 0; jj < 8; ++jj)
                s[jj] = (__bf16)r1[(kc * 32 + kg * 8 + jj) * G_ + ct * 64 + w * 16 + n];
            afr[ct][kc] = s;
        }

    // cell state: 4 cells/lane: (row n, unit w*16 + 4*kg + r)
    float c[4] = {0.f, 0.f, 0.f, 0.f};

    __syncthreads();                         // tokens + zeroed hbuf visible

    // ---- prologue: xstage[0] <- xk(t=0), xstage[1] <- xk(t=1) directly;
    //      pf[1] <- xk(t=2) (written to xstage[2] at step 0).
    float4 pf[2][4];
    {
#pragma unroll
        for (int s = 0; s < 2; ++s) {
            const float* base = embk + (long)tokLDS[prow * TS + s] * G_ + pp * 4;
            float* dst = xstage[s] + prow * XS + pp * 4;
#pragma unroll
            for (int j = 0; j < 4; ++j)
                *(float4*)(dst + j * 64) = *(const float4*)(base + j * 64);
        }
        const float* base2 = embk + (long)tokLDS[prow * TS + 2] * G_ + pp * 4;
#pragma unroll
        for (int j = 0; j < 4; ++j)
            pf[1][j] = *(const float4*)(base2 + j * 64);
    }
    block_sync_lgkm();                       // xstage[0..1] visible

    // step t: consume xstage[rb = t%3]; write xstage[wb = (t+2)%3] from
    // pf[sel^1] (holds xk(t+2), loaded at step t-1); issue loads of xk(t+3)
    // into pf[sel]. sel = t&1. All indices static via 6x unroll.
    auto step = [&](int t, int sel, int rb, int wb) {
        // consumer reads: h^T_{t-1} + xk_t
        const __bf16* hb = hbuf[sel ^ 1];
        bf16x8 b0  = *(const bf16x8*)(hb + n * S_H + kg * 8);
        bf16x8 b1v = *(const bf16x8*)(hb + n * S_H + 32 + kg * 8);
        const float* xrow = xstage[rb] + n * XS + w * 16 + kg * 4;
        floatx4 x0 = *(const floatx4*)(xrow + 0);
        floatx4 x1 = *(const floatx4*)(xrow + 64);
        floatx4 x2 = *(const floatx4*)(xrow + 128);
        floatx4 x3 = *(const floatx4*)(xrow + 192);

        // producer: xstage[wb] <- pf[sel^1] (xk for t+2); vmcnt wait covers
        // loads issued at step t-1 (~a full step ago -> no stall)
        {
            float* dst = xstage[wb] + prow * XS + pp * 4;
            *(float4*)(dst +   0) = pf[sel ^ 1][0];
            *(float4*)(dst +  64) = pf[sel ^ 1][1];
            *(float4*)(dst + 128) = pf[sel ^ 1][2];
            *(float4*)(dst + 192) = pf[sel ^ 1][3];
        }
        // issue coalesced loads of xk(t+3) into pf[sel] (fire-and-forget)
        {
            int tt = t + 3; if (tt > T_ - 1) tt = T_ - 1;
            const float* base = embk + (long)tokLDS[prow * TS + tt] * G_ + pp * 4;
#pragma unroll
            for (int j = 0; j < 4; ++j)
                pf[sel][j] = *(const float4*)(base + j * 64);
        }

        // z^T tiles: acc[ct] = r1^T @ h^T + xk
        floatx4 acc[4];
        acc[0] = x0; acc[1] = x1; acc[2] = x2; acc[3] = x3;
#pragma unroll
        for (int ct = 0; ct < 4; ++ct) {
            acc[ct] = __builtin_amdgcn_mfma_f32_16x16x32_bf16(afr[ct][0], b0,  acc[ct], 0, 0, 0);
            acc[ct] = __builtin_amdgcn_mfma_f32_16x16x32_bf16(afr[ct][1], b1v, acc[ct], 0, 0, 0);
        }

        // gates: 4 dense cells/lane; acc[0]=i, acc[1]=f, acc[2]=g, acc[3]=o
        bf16x4 hv;
#pragma unroll
        for (int r = 0; r < 4; ++r) {
            float zi = acc[0][r], zf = acc[1][r], zg = acc[2][r], zo = acc[3][r];
            float cn = fmaf(sigmoidf_(zf), c[r], sigmoidf_(zi) * tanhf_(zg));
            float hn = sigmoidf_(zo) * tanhf_(cn);
            c[r] = cn;
            hv[r] = (__bf16)hn;
        }
        // h_new: 4 consecutive units -> one b64 write
        *(bf16x4*)(&hbuf[sel][0] + n * S_H + w * 16 + kg * 4) = hv;

        block_sync_lgkm();                   // h_t + xstage[wb] visible
    };

    // 78 = 13*6 steps unrolled x6 (lcm of buffer period 3, parity 2), 2 tail
    for (int t = 0; t < 78; t += 6) {
        step(t + 0, 0, 0, 2);
        step(t + 1, 1, 1, 0);
        step(t + 2, 0, 2, 1);
        step(t + 3, 1, 0, 2);
        step(t + 4, 0, 1, 0);
        step(t + 5, 1, 2, 1);
    }
    step(78, 0, 0, 2);
    step(79, 1, 1, 0);

    // out[b] = sigmoid(h_final[b] . Wd + bd); h_79 in hbuf[1]
    if (tid < 16) {
        const __bf16* hb = hbuf[1] + tid * S_H;
        float s = bd[0];
#pragma unroll
        for (int u = 0; u < U_; ++u) s = fmaf((float)hb[u], Wd[u], s);
        out[bb + tid] = sigmoidf_(s);
    }
}

// ---------------------------------------------------------------------------
extern "C" void kernel_launch(void* const* d_in, const int* in_sizes, int n_in,
                              void* d_out, int out_size, void* d_ws, size_t ws_size,
                              hipStream_t stream) {
    const int*   tokens = (const int*)  d_in[0];
    const float* emb    = (const float*)d_in[1];
    // d_in[2..4] = k0, r0, b0 : dead in the reference (cell0 state unused)
    const float* k1     = (const float*)d_in[5];
    const float* r1     = (const float*)d_in[6];
    const float* b1     = (const float*)d_in[7];
    const float* Wd     = (const float*)d_in[8];
    const float* bd     = (const float*)d_in[9];
    float*       out    = (float*)d_out;

    float* embk = (float*)d_ws;              // V_*G_ floats = 10.24 MB

    embk_kernel<<<((V_ + 63) / 64) * 2, 256, 0, stream>>>(emb, k1, b1, embk);
    lstm_kernel<<<B_ / 16, 256, 0, stream>>>(tokens, embk, r1, Wd, bd, out);
}

// Round 6
// 135.489 us; speedup vs baseline: 1.3043x; 1.3043x over previous
//
#include <hip/hip_runtime.h>
#include <hip/hip_bf16.h>
#include <stdint.h>

// Problem constants
#define B_  4096
#define T_  80
#define E_  100
#define U_  64
#define G_  256    // 4*U
#define V_  10000

#define S_H  72    // hbuf row stride (bf16): 144B rows; b128 reads at the bank floor
#define AS   136   // embk emb-tile LDS stride (bf16)
#define KS2  132   // embk k1-tile ROW-major LDS stride (bf16)
#define TS   81    // token LDS row stride (ints)
#define XS   260   // xstage row stride (floats): 1040B rows (16B aligned); consumer
                   // b128 reads at bank group (n+kg+4w)&7 -> uniform 8 lanes/group = floor

typedef __attribute__((ext_vector_type(8))) __bf16 bf16x8;
typedef __attribute__((ext_vector_type(4))) __bf16 bf16x4;
typedef __attribute__((ext_vector_type(4))) float  floatx4;

__device__ __forceinline__ float sigmoidf_(float x) {
    return __builtin_amdgcn_rcpf(1.f + __expf(-x));
}

__device__ __forceinline__ float tanhf_(float x) {
    // 1 - 2/(e^{2x}+1): monotone, saturates correctly, no NaN
    return fmaf(-2.f, __builtin_amdgcn_rcpf(__expf(2.f * x) + 1.f), 1.f);
}

// global -> LDS direct DMA: each lane contributes 16B; LDS dest = wave-uniform
// base + lane*16 (linear). Tracked by vmcnt. Generic->as(3) via low-32 bits
// (AMDGPU generic LDS address = aperture_hi | lds_offset_lo; CK uses the same).
__device__ __forceinline__ void gload16(const float* gsrc, const float* ldst) {
    __builtin_amdgcn_global_load_lds(
        (const __attribute__((address_space(1))) void*)(uintptr_t)gsrc,
        (__attribute__((address_space(3))) void*)(uintptr_t)ldst,
        16, 0, 0);
}

// ---------------------------------------------------------------------------
// Kernel A (MFMA): embk[v][g] = b1[g] + emb[v] . k1[:,g]   (R5 version, kept)
// ---------------------------------------------------------------------------
__global__ __launch_bounds__(256) void embk_kernel(const float* __restrict__ emb,
                                                   const float* __restrict__ k1,
                                                   const float* __restrict__ b1,
                                                   float* __restrict__ embk) {
    __shared__ __bf16 aLDS[64 * AS];         // 17.4 KB  (emb tile, row-major)
    __shared__ __bf16 kLDS[128 * KS2];       // 33.8 KB  (k1 tile, ROW-major [k][col])

    const int tid  = threadIdx.x;
    const int lane = tid & 63;
    const int w    = tid >> 6;
    const int n    = lane & 15;
    const int kg   = lane >> 4;
    const int v0   = (blockIdx.x >> 1) * 64;
    const int n0   = (blockIdx.x & 1) * 128;
    const int nrows = min(64, V_ - v0);

    for (int i = tid; i < 64 * AS / 8; i += 256) {
        bf16x8 z;
#pragma unroll
        for (int jj = 0; jj < 8; ++jj) z[jj] = (__bf16)0.f;
        *(bf16x8*)(aLDS + i * 8) = z;
    }
    for (int i = tid; i < 28 * KS2; i += 256)
        kLDS[100 * KS2 + i] = (__bf16)0.f;

    const float bv0 = b1[n0 + w * 32 + n];
    const float bv1 = b1[n0 + w * 32 + 16 + n];

    __syncthreads();

    for (int i = tid; i < nrows * 25; i += 256) {
        int r = i / 25, q = i - r * 25;
        float4 ev = *(const float4*)(emb + (long)(v0 + r) * E_ + q * 4);
        bf16x4 bv; bv[0] = (__bf16)ev.x; bv[1] = (__bf16)ev.y;
                   bv[2] = (__bf16)ev.z; bv[3] = (__bf16)ev.w;
        *(bf16x4*)(aLDS + r * AS + q * 4) = bv;
    }
    for (int i = tid; i < 100 * 32; i += 256) {
        int k = i >> 5, cq = (i & 31) * 4;
        float4 kv = *(const float4*)(k1 + (long)k * G_ + n0 + cq);
        bf16x4 bv; bv[0] = (__bf16)kv.x; bv[1] = (__bf16)kv.y;
                   bv[2] = (__bf16)kv.z; bv[3] = (__bf16)kv.w;
        *(bf16x4*)(kLDS + k * KS2 + cq) = bv;
    }
    __syncthreads();

    bf16x8 bfr[2][4];
#pragma unroll
    for (int ct = 0; ct < 2; ++ct)
#pragma unroll
        for (int kc = 0; kc < 4; ++kc) {
            bf16x8 s;
#pragma unroll
            for (int jj = 0; jj < 8; ++jj)
                s[jj] = kLDS[(kc * 32 + kg * 8 + jj) * KS2 + w * 32 + ct * 16 + n];
            bfr[ct][kc] = s;
        }

#pragma unroll
    for (int mt = 0; mt < 4; ++mt) {
        const __bf16* ab = aLDS + (mt * 16 + n) * AS + kg * 8;
        bf16x8 a0 = *(const bf16x8*)(ab + 0);
        bf16x8 a1 = *(const bf16x8*)(ab + 32);
        bf16x8 a2 = *(const bf16x8*)(ab + 64);
        bf16x8 a3 = *(const bf16x8*)(ab + 96);
#pragma unroll
        for (int ct = 0; ct < 2; ++ct) {
            float bv = ct ? bv1 : bv0;
            floatx4 acc = {bv, bv, bv, bv};
            acc = __builtin_amdgcn_mfma_f32_16x16x32_bf16(a0, bfr[ct][0], acc, 0, 0, 0);
            acc = __builtin_amdgcn_mfma_f32_16x16x32_bf16(a1, bfr[ct][1], acc, 0, 0, 0);
            acc = __builtin_amdgcn_mfma_f32_16x16x32_bf16(a2, bfr[ct][2], acc, 0, 0, 0);
            acc = __builtin_amdgcn_mfma_f32_16x16x32_bf16(a3, bfr[ct][3], acc, 0, 0, 0);
#pragma unroll
            for (int r = 0; r < 4; ++r) {
                int v = v0 + mt * 16 + kg * 4 + r;
                if (v < V_) embk[(long)v * G_ + n0 + w * 32 + ct * 16 + n] = acc[r];
            }
        }
    }
}

// ---------------------------------------------------------------------------
// Kernel B per-step schedule (R6): xk rows are DMA'd global->LDS.
//   - consume xstage[RB] (4x ds_read_b128) + h^T_{t-1} (2x ds_read_b128)
//   - issue 4x global_load_lds: row (w*4+j) of xk(t+2) -> xstage[WB]
//     (64 lanes x 16B contiguous per instr: fully coalesced, no per-lane
//      address VALU, no staging registers -> no spill surface)
//   - 8 MFMA, gates (bit-identical to R4), h b64 write
//   - s_waitcnt lgkmcnt(0) vmcnt(4) + s_barrier: LDS drained; ONLY this
//     step's 4 loads may remain in flight => buffer consumed next step is
//     complete. Counted vmcnt, never 0 (T4 pattern), ~1 full step of slack.
// WAR-safe: reads of xstage[WB] happened at step t-1 and were drained by that
// step's lgkmcnt(0) before its barrier; loads are issued after that barrier.
// Indices are TEMPLATE parameters: compile-time by construction (R5's spill
// came from runtime-indexed pf[] in a lambda; rule #20).
// ---------------------------------------------------------------------------
template<int SEL, int RB, int WB>
__device__ __forceinline__ void lstm_step(
        int tt, int n, int kg, int w, int lane,
        const int* __restrict__ tokLDS,
        __bf16 (&hbuf)[2][16 * S_H],
        float (&xstage)[3][16 * XS],
        const bf16x8 (&afr)[4][2],
        const float* __restrict__ embk,
        float (&c)[4]) {
    // consumer reads: h^T_{t-1} + xk_t
    const __bf16* hb = &hbuf[SEL ^ 1][0];
    bf16x8 hb0 = *(const bf16x8*)(hb + n * S_H + kg * 8);
    bf16x8 hb1 = *(const bf16x8*)(hb + n * S_H + 32 + kg * 8);
    const float* xrow = &xstage[RB][0] + n * XS + w * 16 + kg * 4;
    floatx4 a0 = *(const floatx4*)(xrow + 0);
    floatx4 a1 = *(const floatx4*)(xrow + 64);
    floatx4 a2 = *(const floatx4*)(xrow + 128);
    floatx4 a3 = *(const floatx4*)(xrow + 192);

    // producer: DMA xk(t+2) rows w*4..w*4+3 into xstage[WB] (fire-and-forget)
#pragma unroll
    for (int j = 0; j < 4; ++j) {
        int tok = tokLDS[(w * 4 + j) * TS + tt];
        gload16(embk + (long)tok * G_ + (lane << 2),
                &xstage[WB][0] + (w * 4 + j) * XS);
    }

    // z^T tiles: acc[ct] = r1^T @ h^T + xk   (same order as R4 -> bit-identical)
    a0 = __builtin_amdgcn_mfma_f32_16x16x32_bf16(afr[0][0], hb0, a0, 0, 0, 0);
    a0 = __builtin_amdgcn_mfma_f32_16x16x32_bf16(afr[0][1], hb1, a0, 0, 0, 0);
    a1 = __builtin_amdgcn_mfma_f32_16x16x32_bf16(afr[1][0], hb0, a1, 0, 0, 0);
    a1 = __builtin_amdgcn_mfma_f32_16x16x32_bf16(afr[1][1], hb1, a1, 0, 0, 0);
    a2 = __builtin_amdgcn_mfma_f32_16x16x32_bf16(afr[2][0], hb0, a2, 0, 0, 0);
    a2 = __builtin_amdgcn_mfma_f32_16x16x32_bf16(afr[2][1], hb1, a2, 0, 0, 0);
    a3 = __builtin_amdgcn_mfma_f32_16x16x32_bf16(afr[3][0], hb0, a3, 0, 0, 0);
    a3 = __builtin_amdgcn_mfma_f32_16x16x32_bf16(afr[3][1], hb1, a3, 0, 0, 0);

    // gates: 4 dense cells/lane; a0=i, a1=f, a2=g, a3=o  (bit-identical to R4)
    bf16x4 hv;
#pragma unroll
    for (int r = 0; r < 4; ++r) {
        float zi = a0[r], zf = a1[r], zg = a2[r], zo = a3[r];
        float cn = fmaf(sigmoidf_(zf), c[r], sigmoidf_(zi) * tanhf_(zg));
        float hn = sigmoidf_(zo) * tanhf_(cn);
        c[r] = cn;
        hv[r] = (__bf16)hn;
    }
    *(bf16x4*)(&hbuf[SEL][0] + n * S_H + w * 16 + kg * 4) = hv;

    // LDS drained; only this step's 4 DMA loads may remain in flight.
    asm volatile("s_waitcnt lgkmcnt(0) vmcnt(4)\n\ts_barrier" ::: "memory");
}

__global__ __launch_bounds__(256) void lstm_kernel(const int*   __restrict__ tokens,
                                                   const float* __restrict__ embk,
                                                   const float* __restrict__ r1,
                                                   const float* __restrict__ Wd,
                                                   const float* __restrict__ bd,
                                                   float* __restrict__ out) {
    __shared__ int    tokLDS[16 * TS];       // 5.2 KB
    __shared__ __bf16 hbuf[2][16 * S_H];     // 4.6 KB
    __shared__ float  xstage[3][16 * XS];    // 49.9 KB (3-phase rotation)

    const int tid  = threadIdx.x;
    const int lane = tid & 63;
    const int w    = tid >> 6;               // unit block [w*16, w*16+16)
    const int n    = lane & 15;              // batch row (N-operand of MFMA)
    const int kg   = lane >> 4;              // 0..3
    const int bb   = blockIdx.x * 16;

    for (int i = tid; i < 16 * T_; i += 256)
        tokLDS[(i / T_) * TS + (i % T_)] = tokens[bb * T_ + i];
    for (int i = tid; i < 2 * 16 * S_H; i += 256) (&hbuf[0][0])[i] = (__bf16)0.f;

    // A-fragments = r1^T (static): tile ct covers gate-cols ct*64 + w*16 + m
    bf16x8 afr[4][2];
#pragma unroll
    for (int ct = 0; ct < 4; ++ct)
#pragma unroll
        for (int kc = 0; kc < 2; ++kc) {
            bf16x8 s;
#pragma unroll
            for (int jj = 0; jj < 8; ++jj)
                s[jj] = (__bf16)r1[(kc * 32 + kg * 8 + jj) * G_ + ct * 64 + w * 16 + n];
            afr[ct][kc] = s;
        }

    float c[4] = {0.f, 0.f, 0.f, 0.f};

    __syncthreads();      // tokens/hbuf visible; full drain -> clean vmcnt base

    // prologue: DMA xstage[0] (t=0) then xstage[1] (t=1); wait oldest 4 done.
#pragma unroll
    for (int s = 0; s < 2; ++s)
#pragma unroll
        for (int j = 0; j < 4; ++j) {
            int tok = tokLDS[(w * 4 + j) * TS + s];
            gload16(embk + (long)tok * G_ + (lane << 2),
                    &xstage[s][0] + (w * 4 + j) * XS);
        }
    asm volatile("s_waitcnt lgkmcnt(0) vmcnt(4)\n\ts_barrier" ::: "memory");

    // 78 = 13*6 steps (lcm of buffer period 3, parity 2), then 2 tail steps.
    // In-loop tt = t+2 never needs clamping (t <= 77 -> tt <= 79).
    for (int t = 0; t < 78; t += 6) {
        lstm_step<0, 0, 2>(t + 2, n, kg, w, lane, tokLDS, hbuf, xstage, afr, embk, c);
        lstm_step<1, 1, 0>(t + 3, n, kg, w, lane, tokLDS, hbuf, xstage, afr, embk, c);
        lstm_step<0, 2, 1>(t + 4, n, kg, w, lane, tokLDS, hbuf, xstage, afr, embk, c);
        lstm_step<1, 0, 2>(t + 5, n, kg, w, lane, tokLDS, hbuf, xstage, afr, embk, c);
        lstm_step<0, 1, 0>(t + 6, n, kg, w, lane, tokLDS, hbuf, xstage, afr, embk, c);
        lstm_step<1, 2, 1>(t + 7, n, kg, w, lane, tokLDS, hbuf, xstage, afr, embk, c);
    }
    lstm_step<0, 0, 2>(79, n, kg, w, lane, tokLDS, hbuf, xstage, afr, embk, c); // t=78
    lstm_step<1, 1, 0>(79, n, kg, w, lane, tokLDS, hbuf, xstage, afr, embk, c); // t=79

    // drain remaining DMA before touching LDS from the epilogue / ending
    asm volatile("s_waitcnt vmcnt(0)" ::: "memory");

    // out[b] = sigmoid(h_final[b] . Wd + bd); h_79 in hbuf[1]
    if (tid < 16) {
        const __bf16* hb = hbuf[1] + tid * S_H;
        float s = bd[0];
#pragma unroll
        for (int u = 0; u < U_; ++u) s = fmaf((float)hb[u], Wd[u], s);
        out[bb + tid] = sigmoidf_(s);
    }
}

// ---------------------------------------------------------------------------
extern "C" void kernel_launch(void* const* d_in, const int* in_sizes, int n_in,
                              void* d_out, int out_size, void* d_ws, size_t ws_size,
                              hipStream_t stream) {
    const int*   tokens = (const int*)  d_in[0];
    const float* emb    = (const float*)d_in[1];
    // d_in[2..4] = k0, r0, b0 : dead in the reference (cell0 state unused)
    const float* k1     = (const float*)d_in[5];
    const float* r1     = (const float*)d_in[6];
    const float* b1     = (const float*)d_in[7];
    const float* Wd     = (const float*)d_in[8];
    const float* bd     = (const float*)d_in[9];
    float*       out    = (float*)d_out;

    float* embk = (float*)d_ws;              // V_*G_ floats = 10.24 MB

    embk_kernel<<<((V_ + 63) / 64) * 2, 256, 0, stream>>>(emb, k1, b1, embk);
    lstm_kernel<<<B_ / 16, 256, 0, stream>>>(tokens, embk, r1, Wd, bd, out);
}